// Round 4
// baseline (1038.716 us; speedup 1.0000x reference)
//
#include <hip/hip_runtime.h>
#include <hip/hip_bf16.h>
#include <math.h>

// Problem constants
#define NB    64
#define D     256
#define K     1024
#define HW    1024
#define NTOT  65536
// phase-1 (bf16x3 MFMA) score error ~1.5e-7 (sigma). 1e-5 is ~60 sigma; rescue
// count ~200 rows (confirmed round 2: occupancy 1.3%, FETCH 5.8MB).
#define MARGIN 1e-5f

// Output layout (floats)
#define OUT_QOUT   1
#define OUT_PERP   16777217
#define OUT_ENC    16777218
#define OUT_QFLAT  83886082

// ws layout (bytes):
//   0      int rcount
//   16     int hist[1024]
//   4112   float enorm[1024]
//   8208   int idx[65536]            -> 270352
//   270352 int rlist[65536]          -> 532496
//   532496 double lossPartial[2048]  -> 548880
//   548880 ushort efrag[524288]      -> 1597456   (bf16 fragment-layout E, hi+lo)
// efrag layout: [h(2)][ntg(64)][dc(8)][lane(64)][j(8)] bf16
//   element = split_h( emb[ k = ntg*16 + (lane&15) ][ d = dc*32 + (lane>>4)*8 + j ] )

typedef __attribute__((ext_vector_type(8))) short bf16x8;
typedef __attribute__((ext_vector_type(4))) float f32x4;

__global__ void enorm_kernel(const float* __restrict__ emb, float* __restrict__ enorm) {
    int k = blockIdx.x * 256 + threadIdx.x;
    const float4* row = (const float4*)(emb + (size_t)k * D);
    float s = 0.f;
    #pragma unroll
    for (int q = 0; q < D / 4; q++) {
        float4 v = row[q];
        s += v.x * v.x + v.y * v.y + v.z * v.z + v.w * v.w;
    }
    enorm[k] = s;
}

// ---- Pre-split E into MFMA B-fragment layout (hi/lo bf16), once ----
__global__ void esplit_kernel(const float* __restrict__ emb, ushort* __restrict__ efrag) {
    const int ntg = blockIdx.x;          // 64 blocks: one 16-col k-tile each
    const int t = threadIdx.x;
    __shared__ float sEm[16 * 260];      // 16 rows x 256 d, pad 4

    // stage emb rows k = ntg*16 .. +15
    {
        const int row = t >> 4, seg = t & 15;
        const float4* src = (const float4*)(emb + (size_t)(ntg * 16 + row) * D + seg * 16);
        float4* dst = (float4*)(sEm + row * 260 + seg * 16);
        #pragma unroll
        for (int q = 0; q < 4; q++) dst[q] = src[q];
    }
    __syncthreads();

    const int w = t >> 6, lane = t & 63;
    for (int fb = w; fb < 16; fb += 4) {         // fb = h*8 + dc
        const int h = fb >> 3, dc = fb & 7;
        const float* srcp = sEm + (lane & 15) * 260 + dc * 32 + (lane >> 4) * 8;
        ushort o[8];
        #pragma unroll
        for (int j = 0; j < 8; j++) {
            float x = srcp[j];
            __hip_bfloat16 hb = __float2bfloat16(x);
            if (h == 0) { o[j] = *(ushort*)&hb; }
            else {
                float hf = __bfloat162float(hb);
                __hip_bfloat16 lb = __float2bfloat16(x - hf);
                o[j] = *(ushort*)&lb;
            }
        }
        ushort* dst = efrag + ((size_t)(h * 64 + ntg) * 8 + dc) * 512 + lane * 8;
        *(int4*)dst = *(int4*)o;
    }
}

// ---- Phase 1: MFMA bf16x3 scores + in-kernel argmin (min1, idx, min2) ----
// 32 rows/block, 4 blocks/CU. Waves split K; per kp each wave covers 4 n-tiles
// in 2 halves (nh) of 2 tiles, dc outer / nh inner, A-frags hoisted per dc,
// B double-buffered across (dc,nh) steps with wrap-around prefetch so the
// epilogue hides the next-kp B latency. Hot live set ~60 arch VGPRs + 32 AGPR
// -> no scratch even if the compiler clamps the arch file to 64 (round-3 obs).
__global__ __launch_bounds__(256, 4) void score_mfma_kernel(
    const float* __restrict__ in, const ushort* __restrict__ efrag,
    const float* __restrict__ enorm, int* __restrict__ idx,
    int* __restrict__ rcount, int* __restrict__ rlist)
{
    __shared__ ushort sA[16384];   // [h(2)][mt(2)][dc(8)][lane(64)][j(8)] bf16 = 32KB

    const int t = threadIdx.x;
    const int n0 = blockIdx.x * 32;
    const int b = n0 >> 10, p0 = n0 & 1023;
    const int w = t >> 6, lane = t & 63;

    // Stage A (vectorized LDS writes, conflict-free): thread handles 4 fragment
    // blocks fb = w*4+i (fb = mt*8+dc); for each, it owns fragment-lane L=lane,
    // j=0..7 -> 8 consecutive d at one row -> 2x ds_write_b128 (hi,lo).
    {
        #pragma unroll
        for (int i = 0; i < 4; i++) {
            const int fb = w * 4 + i;            // 0..15
            const int mt = fb >> 3, dc = fb & 7;
            const int m  = mt * 16 + (lane & 15);
            const int d0 = dc * 32 + (lane >> 4) * 8;
            const float* src = in + (size_t)b * (D * HW) + (size_t)d0 * HW + p0 + m;
            ushort oh[8], ol[8];
            #pragma unroll
            for (int j = 0; j < 8; j++) {
                const float x = src[(size_t)j * HW];
                __hip_bfloat16 hb = __float2bfloat16(x);
                const float hf = __bfloat162float(hb);
                __hip_bfloat16 lb = __float2bfloat16(x - hf);
                oh[j] = *(ushort*)&hb;
                ol[j] = *(ushort*)&lb;
            }
            ushort* dh = sA + ((0 * 2 + mt) * 8 + dc) * 512 + lane * 8;
            ushort* dl = sA + ((1 * 2 + mt) * 8 + dc) * 512 + lane * 8;
            *(int4*)dh = *(int4*)oh;
            *(int4*)dl = *(int4*)ol;
        }
    }
    __syncthreads();

    // this lane's running argmin for its ONE owned row:
    //   owned (mt,r) = ((lane&15)>>2, lane&3), valid when (lane&15)<8;
    //   row = mt*16 + (lane>>4)*4 + r
    float rm1 = 3.4e38f, rm2 = 3.4e38f; int ri = 0;

    // B fragment address helper (elements): column c of this wave at (kp,dc)
    const ushort* efragLo = efrag + 262144;

    // preload (kp=0, dc=0, nh=0) -> columns 0,1
    bf16x8 bh[2], bl[2], nbh[2], nbl[2];
    {
        const size_t o0 = ((size_t)((0 * 16 + w * 4 + 0) * 8 + 0)) * 512 + lane * 8;
        const size_t o1 = ((size_t)((0 * 16 + w * 4 + 1) * 8 + 0)) * 512 + lane * 8;
        bh[0] = *(const bf16x8*)(efrag + o0);  bl[0] = *(const bf16x8*)(efragLo + o0);
        bh[1] = *(const bf16x8*)(efrag + o1);  bl[1] = *(const bf16x8*)(efragLo + o1);
    }

    for (int kp = 0; kp < 4; kp++) {
        f32x4 acc[2][4];
        #pragma unroll
        for (int mt = 0; mt < 2; mt++)
            #pragma unroll
            for (int c = 0; c < 4; c++) acc[mt][c] = (f32x4){0.f, 0.f, 0.f, 0.f};

        #pragma unroll
        for (int dc = 0; dc < 8; dc++) {
            // A-frags for this dc, reused by both nh halves
            bf16x8 ah[2], al[2];
            #pragma unroll
            for (int mt = 0; mt < 2; mt++) {
                ah[mt] = *(const bf16x8*)(sA + ((0 * 2 + mt) * 8 + dc) * 512 + lane * 8);
                al[mt] = *(const bf16x8*)(sA + ((1 * 2 + mt) * 8 + dc) * 512 + lane * 8);
            }
            #pragma unroll
            for (int nh = 0; nh < 2; nh++) {
                // prefetch next (dc,nh) step; at kp end wrap to next kp (dc=0,nh=0).
                {
                    int nkp = kp, ndc = dc, nnh = nh + 1;
                    if (nnh == 2) { nnh = 0; ndc = dc + 1; if (ndc == 8) { ndc = 0; nkp = (kp + 1) & 3; } }
                    const int ntg0 = nkp * 16 + w * 4 + nnh * 2;
                    const size_t o0 = ((size_t)(ntg0 * 8 + ndc)) * 512 + lane * 8;
                    const size_t o1 = o0 + 8 * 512;   // ntg0+1
                    nbh[0] = *(const bf16x8*)(efrag + o0);  nbl[0] = *(const bf16x8*)(efragLo + o0);
                    nbh[1] = *(const bf16x8*)(efrag + o1);  nbl[1] = *(const bf16x8*)(efragLo + o1);
                }
                #pragma unroll
                for (int mt = 0; mt < 2; mt++) {
                    #pragma unroll
                    for (int ntl = 0; ntl < 2; ntl++) {
                        const int c = nh * 2 + ntl;
                        acc[mt][c] = __builtin_amdgcn_mfma_f32_16x16x32_bf16(al[mt], bh[ntl], acc[mt][c], 0, 0, 0);
                        acc[mt][c] = __builtin_amdgcn_mfma_f32_16x16x32_bf16(ah[mt], bh[ntl], acc[mt][c], 0, 0, 0);
                        acc[mt][c] = __builtin_amdgcn_mfma_f32_16x16x32_bf16(ah[mt], bl[ntl], acc[mt][c], 0, 0, 0);
                    }
                }
                bh[0] = nbh[0]; bl[0] = nbl[0];
                bh[1] = nbh[1]; bl[1] = nbl[1];
            }
        }

        // epilogue: scores + per-row reduce (16 lanes per quad hold 16 k-cols of one row);
        // after the butterfly all 16 quad lanes hold the reduced triple -> owner lane merges.
        float env[4]; int kc[4];
        #pragma unroll
        for (int c = 0; c < 4; c++) {
            kc[c] = kp * 256 + (w * 4 + c) * 16 + (lane & 15);
            env[c] = enorm[kc[c]];
        }
        #pragma unroll
        for (int mt = 0; mt < 2; mt++)
            #pragma unroll
            for (int r = 0; r < 4; r++) {
                float m1 = 3.4e38f, m2 = 3.4e38f; int i1 = 0;
                #pragma unroll
                for (int c = 0; c < 4; c++) {
                    float s = env[c] - 2.0f * acc[mt][c][r];
                    if (s < m1) { m2 = m1; m1 = s; i1 = kc[c]; }
                    else if (s < m2) m2 = s;
                }
                #pragma unroll
                for (int mask = 1; mask <= 8; mask <<= 1) {
                    float o1 = __shfl_xor(m1, mask, 64);
                    int   oi = __shfl_xor(i1, mask, 64);
                    float o2 = __shfl_xor(m2, mask, 64);
                    float n2 = fminf(fminf(m2, o2), fmaxf(m1, o1));
                    if (o1 < m1 || (o1 == m1 && oi < i1)) { m1 = o1; i1 = oi; }
                    m2 = n2;
                }
                if ((lane & 15) == mt * 4 + r) {
                    float n2 = fminf(fminf(rm2, m2), fmaxf(rm1, m1));
                    if (m1 < rm1 || (m1 == rm1 && i1 < ri)) { rm1 = m1; ri = i1; }
                    rm2 = n2;
                }
            }
    }

    // cross-wave merge via LDS (alias sA; all MFMA A-reads done)
    __syncthreads();
    float* sM1 = (float*)sA;           // [4][32]
    float* sM2 = sM1 + 128;
    int*   sI  = (int*)(sM2 + 128);
    if ((lane & 15) < 8) {
        const int row = ((lane & 15) >> 2) * 16 + (lane >> 4) * 4 + (lane & 3);
        sM1[w * 32 + row] = rm1;
        sM2[w * 32 + row] = rm2;
        sI [w * 32 + row] = ri;
    }
    __syncthreads();
    if (t < 32) {
        float b1 = sM1[t], b2 = sM2[t]; int bi = sI[t];
        #pragma unroll
        for (int ww = 1; ww < 4; ww++) {
            float a1 = sM1[ww * 32 + t], a2 = sM2[ww * 32 + t]; int ai = sI[ww * 32 + t];
            float n2 = fminf(fminf(b2, a2), fmaxf(b1, a1));
            if (a1 < b1 || (a1 == b1 && ai < bi)) { b1 = a1; bi = ai; }
            b2 = n2;
        }
        const int n = n0 + t;
        idx[n] = bi;
        if (b2 - b1 < MARGIN) {
            int pos = atomicAdd(rcount, 1);
            rlist[pos] = n;
        }
    }
}

// ---- Phase 2: fp64 re-score of ambiguous rows (true argmin, lowest-idx ties) ----
// kk OUTER (contiguous per-lane emb walk -> 16x L1 line reuse; round-2's kk-inner
// order gathered 64 distinct lines/instr and cost 456us of pure latency).
// float4 loads (16 lines/instr), shfl with compile-time lane -> v_readlane/SGPR
// broadcast, 4 independent fp64 chains to break the accumulation dependency.
__global__ void rescue_kernel(const float* __restrict__ in, const float* __restrict__ emb,
                              const int* __restrict__ rcount, const int* __restrict__ rlist,
                              int* __restrict__ idx)
{
    const int wid = blockIdx.x * 4 + (threadIdx.x >> 6);
    const int lane = threadIdx.x & 63;
    const int count = *rcount;
    for (int li = wid; li < count; li += 512 * 4) {
        const int n = rlist[li];
        const int b = n >> 10, p = n & 1023;
        const float* f = in + (size_t)b * (D * HW) + p;
        float fr[4];
        #pragma unroll
        for (int q = 0; q < 4; q++) fr[q] = f[(size_t)(lane + q * 64) * HW];
        double bm = 1e300; int bk = 0;
        #pragma unroll 1
        for (int kk = 0; kk < 16; kk++) {          // kk ascending -> lowest k on ties
            const int k = lane + kk * 64;
            const float4* er4 = (const float4*)(emb + (size_t)k * D);
            double sc[4];
            #pragma unroll
            for (int q = 0; q < 4; q++) sc[q] = 0.0;
            #pragma unroll
            for (int q = 0; q < 4; q++) {
                #pragma unroll
                for (int f4 = 0; f4 < 16; f4++) {
                    const float4 ev4 = er4[q * 16 + f4];
                    #pragma unroll
                    for (int e = 0; e < 4; e++) {
                        const int dl = f4 * 4 + e;
                        const double fv = (double)__shfl(fr[q], dl, 64);
                        const double ev = (double)((const float*)&ev4)[e];
                        sc[q] += ev * (ev - 2.0 * fv);
                    }
                }
            }
            const double s = (sc[0] + sc[1]) + (sc[2] + sc[3]);
            if (s < bm) { bm = s; bk = k; }
        }
        #pragma unroll
        for (int off = 32; off >= 1; off >>= 1) {
            double om = __shfl_xor(bm, off, 64);
            int    ok = __shfl_xor(bk, off, 64);
            if (om < bm || (om == bm && ok < bk)) { bm = om; bk = ok; }
        }
        if (lane == 0) idx[n] = bk;
    }
}

// ---- Fused outputs: qout(NCHW) + loss partials + qflat + FULL one-hot + hist ----
// Block = 32 rows x 256 d, emb rows staged in LDS (coalesced gather).
// enc is written densely here (268MB streamed) -> the separate 268MB memset pass is gone.
__global__ __launch_bounds__(256) void outputs_kernel(
    const float* __restrict__ in, const float* __restrict__ emb,
    const int* __restrict__ idx, float* __restrict__ out,
    double* __restrict__ lossPartial, int* __restrict__ hist)
{
    __shared__ int skv[32];
    __shared__ float sQ[32 * 260];
    __shared__ double sred[4];

    const int t = threadIdx.x;
    const int n0 = blockIdx.x * 32;
    const int b = n0 >> 10, p0 = n0 & 1023;

    if (t < 32) skv[t] = idx[n0 + t];
    __syncthreads();

    // stage emb rows (coalesced per 8-thread group) + write qflat directly
    {
        const int r = t >> 3, c0 = (t & 7) * 32;
        const int kv = skv[r];
        const float4* src = (const float4*)(emb + (size_t)kv * D + c0);
        float4* dstL = (float4*)(sQ + r * 260 + c0);
        float4* dstG = (float4*)(out + OUT_QFLAT + (size_t)(n0 + r) * D + c0);
        #pragma unroll
        for (int g = 0; g < 8; g++) {
            float4 v = src[g];
            dstL[g] = v;
            dstG[g] = v;
        }
    }
    // enc one-hot: dense coalesced write (thread t owns cols [4t,4t+4) of every row)
    {
        float* encBase = out + OUT_ENC + (size_t)n0 * K;
        const int c0 = t * 4;
        #pragma unroll 4
        for (int r = 0; r < 32; r++) {
            const int kv = skv[r];
            float4 v = make_float4(0.f, 0.f, 0.f, 0.f);
            if (kv >= c0 && kv < c0 + 4) ((float*)&v)[kv - c0] = 1.0f;
            *(float4*)(encBase + (size_t)r * K + c0) = v;
        }
    }
    if (t < 32) atomicAdd(&hist[skv[t]], 1);
    __syncthreads();

    // qout NCHW + loss: lanes cover p (coalesced 128B per 32-lane group)
    const int p = t & 31, dg = t >> 5;
    double acc = 0.0;
    const size_t obase = (size_t)b * (D * HW) + p0 + p;
    #pragma unroll
    for (int dd = 0; dd < 32; dd++) {
        const int d = dg * 32 + dd;
        const float q = sQ[p * 260 + d];
        const float x = in[obase + (size_t)d * HW];
        out[OUT_QOUT + obase + (size_t)d * HW] = q;
        const float df = q - x;
        acc += (double)(df * df);
    }
    #pragma unroll
    for (int off = 32; off >= 1; off >>= 1) acc += __shfl_xor(acc, off, 64);
    if ((t & 63) == 0) sred[t >> 6] = acc;
    __syncthreads();
    if (t == 0) lossPartial[blockIdx.x] = sred[0] + sred[1] + sred[2] + sred[3];
}

__global__ void finalize_kernel(const int* __restrict__ hist, const double* __restrict__ lossPartial,
                                float* __restrict__ out)
{
    const int t = threadIdx.x;
    double s = 0.0;
    #pragma unroll
    for (int q = 0; q < 4; q++) {
        const int c = hist[t + q * 256];
        const double p = (double)c / (double)NTOT;
        s += p * log(p + 1e-10);
    }
    double l = 0.0;
    #pragma unroll
    for (int q = 0; q < 8; q++) l += lossPartial[t + q * 256];
    #pragma unroll
    for (int off = 32; off >= 1; off >>= 1) {
        s += __shfl_xor(s, off, 64);
        l += __shfl_xor(l, off, 64);
    }
    __shared__ double sr[4], lr[4];
    if ((t & 63) == 0) { sr[t >> 6] = s; lr[t >> 6] = l; }
    __syncthreads();
    if (t == 0) {
        out[0] = (float)(1.25 * (lr[0] + lr[1] + lr[2] + lr[3]) / (double)(NTOT * (size_t)D));
        out[OUT_PERP] = (float)exp(-(sr[0] + sr[1] + sr[2] + sr[3]));
    }
}

extern "C" void kernel_launch(void* const* d_in, const int* in_sizes, int n_in,
                              void* d_out, int out_size, void* d_ws, size_t ws_size,
                              hipStream_t stream)
{
    const float* in  = (const float*)d_in[0];   // [64,256,32,32] fp32
    const float* emb = (const float*)d_in[1];   // [1024,256] fp32
    float* out = (float*)d_out;
    char* ws = (char*)d_ws;

    int*    rcount      = (int*)(ws + 0);
    int*    hist        = (int*)(ws + 16);
    float*  enorm       = (float*)(ws + 4112);
    int*    idx         = (int*)(ws + 8208);
    int*    rlist       = (int*)(ws + 270352);
    double* lossPartial = (double*)(ws + 532496);
    ushort* efrag       = (ushort*)(ws + 548880);

    hipMemsetAsync(ws, 0, 8208, stream);                                   // rcount + hist

    enorm_kernel<<<K / 256, 256, 0, stream>>>(emb, enorm);
    esplit_kernel<<<K / 16, 256, 0, stream>>>(emb, efrag);
    score_mfma_kernel<<<NTOT / 32, 256, 0, stream>>>(in, efrag, enorm, idx, rcount, rlist);
    rescue_kernel<<<512, 256, 0, stream>>>(in, emb, rcount, rlist, idx);
    outputs_kernel<<<NTOT / 32, 256, 0, stream>>>(in, emb, idx, out, lossPartial, hist);
    finalize_kernel<<<1, 256, 0, stream>>>(hist, lossPartial, out);
}

// Round 5
// 912.589 us; speedup vs baseline: 1.1382x; 1.1382x over previous
//
#include <hip/hip_runtime.h>
#include <hip/hip_bf16.h>
#include <math.h>

// Problem constants
#define NB    64
#define D     256
#define K     1024
#define HW    1024
#define NTOT  65536
// phase-1 (bf16x3 MFMA) score error ~1.5e-7 (sigma). 1e-5 is ~60 sigma; rescue
// count ~200 rows (confirmed round 2: occupancy 1.3%, FETCH 5.8MB).
#define MARGIN 1e-5f

// Output layout (floats)
#define OUT_QOUT   1
#define OUT_PERP   16777217
#define OUT_ENC    16777218
#define OUT_QFLAT  83886082

// ws layout (bytes):
//   0      int rcount
//   16     int hist[1024]
//   4112   float enorm[1024]
//   8208   int idx[65536]            -> 270352
//   270352 int rlist[65536]          -> 532496
//   532496 double lossPartial[2048]  -> 548880
//   548880 ushort efrag[524288]      -> 1597456   (bf16 fragment-layout E, hi+lo)
// efrag layout: [h(2)][ntg(64)][dc(8)][lane(64)][j(8)] bf16
//   element = split_h( emb[ k = ntg*16 + (lane&15) ][ d = dc*32 + (lane>>4)*8 + j ] )

typedef __attribute__((ext_vector_type(8))) short bf16x8;
typedef __attribute__((ext_vector_type(4))) float f32x4;

__global__ void enorm_kernel(const float* __restrict__ emb, float* __restrict__ enorm) {
    int k = blockIdx.x * 256 + threadIdx.x;
    const float4* row = (const float4*)(emb + (size_t)k * D);
    float s = 0.f;
    #pragma unroll
    for (int q = 0; q < D / 4; q++) {
        float4 v = row[q];
        s += v.x * v.x + v.y * v.y + v.z * v.z + v.w * v.w;
    }
    enorm[k] = s;
}

// ---- Pre-split E into MFMA B-fragment layout (hi/lo bf16), once ----
__global__ void esplit_kernel(const float* __restrict__ emb, ushort* __restrict__ efrag) {
    const int ntg = blockIdx.x;          // 64 blocks: one 16-col k-tile each
    const int t = threadIdx.x;
    __shared__ float sEm[16 * 260];      // 16 rows x 256 d, pad 4

    // stage emb rows k = ntg*16 .. +15
    {
        const int row = t >> 4, seg = t & 15;
        const float4* src = (const float4*)(emb + (size_t)(ntg * 16 + row) * D + seg * 16);
        float4* dst = (float4*)(sEm + row * 260 + seg * 16);
        #pragma unroll
        for (int q = 0; q < 4; q++) dst[q] = src[q];
    }
    __syncthreads();

    const int w = t >> 6, lane = t & 63;
    for (int fb = w; fb < 16; fb += 4) {         // fb = h*8 + dc
        const int h = fb >> 3, dc = fb & 7;
        const float* srcp = sEm + (lane & 15) * 260 + dc * 32 + (lane >> 4) * 8;
        ushort o[8];
        #pragma unroll
        for (int j = 0; j < 8; j++) {
            float x = srcp[j];
            __hip_bfloat16 hb = __float2bfloat16(x);
            if (h == 0) { o[j] = *(ushort*)&hb; }
            else {
                float hf = __bfloat162float(hb);
                __hip_bfloat16 lb = __float2bfloat16(x - hf);
                o[j] = *(ushort*)&lb;
            }
        }
        ushort* dst = efrag + ((size_t)(h * 64 + ntg) * 8 + dc) * 512 + lane * 8;
        *(int4*)dst = *(int4*)o;
    }
}

// ---- Phase 1: MFMA bf16x3 scores + in-kernel argmin (min1, idx, min2) ----
// 32 rows/block. Key changes vs round 4 (anti-spill):
//  (a) NO per-kp butterfly epilogue: per-lane running (m1,m2,i) for all 8
//      (mt,r) combos (24 regs, shuffle-free in the loop); the 8 butterflies
//      run ONCE after the K-loop when no loop state is live.
//  (b) amdgpu_waves_per_eu(2,2): pins 256 unified regs/wave so the backend
//      stops clamping the arch file to 64 and spilling (rounds 0-4: WRITE_SIZE
//      155-534MB of scratch traffic, = kernel runtime at observed HBM BW).
//  (c) B-fragments in a 4-deep compile-time rotation (64 regs): ~18 MFMAs of
//      issue distance covers the ~200cyc L2 latency at 2 waves/EU.
__global__ void __attribute__((amdgpu_flat_work_group_size(256, 256), amdgpu_waves_per_eu(2, 2)))
score_mfma_kernel(
    const float* __restrict__ in, const ushort* __restrict__ efrag,
    const float* __restrict__ enorm, int* __restrict__ idx,
    int* __restrict__ rcount, int* __restrict__ rlist)
{
    __shared__ ushort sA[16384];   // [h(2)][mt(2)][dc(8)][lane(64)][j(8)] bf16 = 32KB

    const int t = threadIdx.x;
    const int n0 = blockIdx.x * 32;
    const int b = n0 >> 10, p0 = n0 & 1023;
    const int w = t >> 6, lane = t & 63;

    // Stage A (vectorized LDS writes, conflict-free; verified round 4).
    {
        #pragma unroll
        for (int i = 0; i < 4; i++) {
            const int fb = w * 4 + i;            // 0..15
            const int mt = fb >> 3, dc = fb & 7;
            const int m  = mt * 16 + (lane & 15);
            const int d0 = dc * 32 + (lane >> 4) * 8;
            const float* src = in + (size_t)b * (D * HW) + (size_t)d0 * HW + p0 + m;
            ushort oh[8], ol[8];
            #pragma unroll
            for (int j = 0; j < 8; j++) {
                const float x = src[(size_t)j * HW];
                __hip_bfloat16 hb = __float2bfloat16(x);
                const float hf = __bfloat162float(hb);
                __hip_bfloat16 lb = __float2bfloat16(x - hf);
                oh[j] = *(ushort*)&hb;
                ol[j] = *(ushort*)&lb;
            }
            ushort* dh = sA + ((0 * 2 + mt) * 8 + dc) * 512 + lane * 8;
            ushort* dl = sA + ((1 * 2 + mt) * 8 + dc) * 512 + lane * 8;
            *(int4*)dh = *(int4*)oh;
            *(int4*)dl = *(int4*)ol;
        }
    }
    __syncthreads();

    // per-lane running argmin for all 8 (mt,r) combos; q = mt*4 + r.
    // lane's scores live at rows mt*16 + (lane>>4)*4 + r, col kc (see epilogue).
    float rm1[8], rm2[8]; int ri[8];
    #pragma unroll
    for (int q = 0; q < 8; q++) { rm1[q] = 3.4e38f; rm2[q] = 3.4e38f; ri[q] = 0; }

    const ushort* efragLo = efrag + 262144;

    for (int kp = 0; kp < 4; kp++) {
        f32x4 acc[2][4];
        #pragma unroll
        for (int mt = 0; mt < 2; mt++)
            #pragma unroll
            for (int c = 0; c < 4; c++) acc[mt][c] = (f32x4){0.f, 0.f, 0.f, 0.f};

        // B rotation: step s (0..15) covers dc = s>>1, col-pair cp = s&1
        // (cols c = cp*2, cp*2+1). Buffer index s&3; prefetch depth 3 steps.
        bf16x8 Bh[4][2], Bl[4][2];
        #pragma unroll
        for (int s = 0; s < 3; s++) {
            const int dc = s >> 1, cp = s & 1;
            const int ntg0 = kp * 16 + w * 4 + cp * 2;
            const size_t o0 = ((size_t)(ntg0 * 8 + dc)) * 512 + lane * 8;
            Bh[s][0] = *(const bf16x8*)(efrag + o0);
            Bl[s][0] = *(const bf16x8*)(efragLo + o0);
            Bh[s][1] = *(const bf16x8*)(efrag + o0 + 8 * 512);
            Bl[s][1] = *(const bf16x8*)(efragLo + o0 + 8 * 512);
        }

        bf16x8 ah[2], al[2];
        #pragma unroll
        for (int s = 0; s < 16; s++) {
            const int dc = s >> 1, cp = s & 1;
            if (s + 3 < 16) {
                const int s2 = s + 3, dc2 = s2 >> 1, cp2 = s2 & 1, bs2 = s2 & 3;
                const int ntg0 = kp * 16 + w * 4 + cp2 * 2;
                const size_t o0 = ((size_t)(ntg0 * 8 + dc2)) * 512 + lane * 8;
                Bh[bs2][0] = *(const bf16x8*)(efrag + o0);
                Bl[bs2][0] = *(const bf16x8*)(efragLo + o0);
                Bh[bs2][1] = *(const bf16x8*)(efrag + o0 + 8 * 512);
                Bl[bs2][1] = *(const bf16x8*)(efragLo + o0 + 8 * 512);
            }
            if (cp == 0) {   // A-frags for this dc, reused by both col-pairs
                #pragma unroll
                for (int mt = 0; mt < 2; mt++) {
                    ah[mt] = *(const bf16x8*)(sA + ((0 * 2 + mt) * 8 + dc) * 512 + lane * 8);
                    al[mt] = *(const bf16x8*)(sA + ((1 * 2 + mt) * 8 + dc) * 512 + lane * 8);
                }
            }
            const int bs = s & 3;
            #pragma unroll
            for (int mt = 0; mt < 2; mt++) {
                #pragma unroll
                for (int cc = 0; cc < 2; cc++) {
                    const int c = cp * 2 + cc;
                    acc[mt][c] = __builtin_amdgcn_mfma_f32_16x16x32_bf16(al[mt], Bh[bs][cc], acc[mt][c], 0, 0, 0);
                    acc[mt][c] = __builtin_amdgcn_mfma_f32_16x16x32_bf16(ah[mt], Bh[bs][cc], acc[mt][c], 0, 0, 0);
                    acc[mt][c] = __builtin_amdgcn_mfma_f32_16x16x32_bf16(ah[mt], Bl[bs][cc], acc[mt][c], 0, 0, 0);
                }
            }
        }

        // shuffle-free per-lane merge; kc strictly ascending over (kp,c) and
        // strict '<' keep lowest-index ties, exactly as before.
        #pragma unroll
        for (int c = 0; c < 4; c++) {
            const int kcc = kp * 256 + (w * 4 + c) * 16 + (lane & 15);
            const float envc = enorm[kcc];
            #pragma unroll
            for (int mt = 0; mt < 2; mt++)
                #pragma unroll
                for (int r = 0; r < 4; r++) {
                    const int q = mt * 4 + r;
                    const float s = envc - 2.0f * acc[mt][c][r];
                    if (s < rm1[q]) { rm2[q] = rm1[q]; rm1[q] = s; ri[q] = kcc; }
                    else if (s < rm2[q]) rm2[q] = s;
                }
        }
    }

    // 8 butterflies, once, after the K-loop (no loop state live).
    float f1 = 3.4e38f, f2 = 3.4e38f; int fi = 0;
    #pragma unroll
    for (int q = 0; q < 8; q++) {
        float m1 = rm1[q], m2 = rm2[q]; int i1 = ri[q];
        #pragma unroll
        for (int mask = 1; mask <= 8; mask <<= 1) {
            float o1 = __shfl_xor(m1, mask, 64);
            int   oi = __shfl_xor(i1, mask, 64);
            float o2 = __shfl_xor(m2, mask, 64);
            float n2 = fminf(fminf(m2, o2), fmaxf(m1, o1));
            if (o1 < m1 || (o1 == m1 && oi < i1)) { m1 = o1; i1 = oi; }
            m2 = n2;
        }
        if ((lane & 15) == q) { f1 = m1; f2 = m2; fi = i1; }
    }

    // cross-wave merge via LDS (alias sA; all MFMA A-reads done)
    __syncthreads();
    float* sM1 = (float*)sA;           // [4][32]
    float* sM2 = sM1 + 128;
    int*   sI  = (int*)(sM2 + 128);
    if ((lane & 15) < 8) {
        const int q = lane & 15;       // owner's combo: mt = q>>2, r = q&3
        const int row = (q >> 2) * 16 + (lane >> 4) * 4 + (q & 3);
        sM1[w * 32 + row] = f1;
        sM2[w * 32 + row] = f2;
        sI [w * 32 + row] = fi;
    }
    __syncthreads();
    if (t < 32) {
        float b1 = sM1[t], b2 = sM2[t]; int bi = sI[t];
        #pragma unroll
        for (int ww = 1; ww < 4; ww++) {
            float a1 = sM1[ww * 32 + t], a2 = sM2[ww * 32 + t]; int ai = sI[ww * 32 + t];
            float n2 = fminf(fminf(b2, a2), fmaxf(b1, a1));
            if (a1 < b1 || (a1 == b1 && ai < bi)) { b1 = a1; bi = ai; }
            b2 = n2;
        }
        const int n = n0 + t;
        idx[n] = bi;
        if (b2 - b1 < MARGIN) {
            int pos = atomicAdd(rcount, 1);
            rlist[pos] = n;
        }
    }
}

// ---- Phase 2: fp64 re-score of ambiguous rows (true argmin, lowest-idx ties) ----
// kk OUTER (contiguous per-lane emb walk -> 16x L1 line reuse), float4 loads,
// shfl with compile-time lane -> readlane broadcast, 4 independent fp64 chains.
__global__ void rescue_kernel(const float* __restrict__ in, const float* __restrict__ emb,
                              const int* __restrict__ rcount, const int* __restrict__ rlist,
                              int* __restrict__ idx)
{
    const int wid = blockIdx.x * 4 + (threadIdx.x >> 6);
    const int lane = threadIdx.x & 63;
    const int count = *rcount;
    for (int li = wid; li < count; li += 512 * 4) {
        const int n = rlist[li];
        const int b = n >> 10, p = n & 1023;
        const float* f = in + (size_t)b * (D * HW) + p;
        float fr[4];
        #pragma unroll
        for (int q = 0; q < 4; q++) fr[q] = f[(size_t)(lane + q * 64) * HW];
        double bm = 1e300; int bk = 0;
        #pragma unroll 1
        for (int kk = 0; kk < 16; kk++) {          // kk ascending -> lowest k on ties
            const int k = lane + kk * 64;
            const float4* er4 = (const float4*)(emb + (size_t)k * D);
            double sc[4];
            #pragma unroll
            for (int q = 0; q < 4; q++) sc[q] = 0.0;
            #pragma unroll
            for (int q = 0; q < 4; q++) {
                #pragma unroll
                for (int f4 = 0; f4 < 16; f4++) {
                    const float4 ev4 = er4[q * 16 + f4];
                    #pragma unroll
                    for (int e = 0; e < 4; e++) {
                        const int dl = f4 * 4 + e;
                        const double fv = (double)__shfl(fr[q], dl, 64);
                        const double ev = (double)((const float*)&ev4)[e];
                        sc[q] += ev * (ev - 2.0 * fv);
                    }
                }
            }
            const double s = (sc[0] + sc[1]) + (sc[2] + sc[3]);
            if (s < bm) { bm = s; bk = k; }
        }
        #pragma unroll
        for (int off = 32; off >= 1; off >>= 1) {
            double om = __shfl_xor(bm, off, 64);
            int    ok = __shfl_xor(bk, off, 64);
            if (om < bm || (om == bm && ok < bk)) { bm = om; bk = ok; }
        }
        if (lane == 0) idx[n] = bk;
    }
}

// ---- Fused outputs: qout(NCHW) + loss partials + qflat + FULL one-hot + hist ----
// Block = 32 rows x 256 d, emb rows staged in LDS (coalesced gather).
// enc is written densely here (268MB streamed) -> the separate 268MB memset pass is gone.
__global__ __launch_bounds__(256) void outputs_kernel(
    const float* __restrict__ in, const float* __restrict__ emb,
    const int* __restrict__ idx, float* __restrict__ out,
    double* __restrict__ lossPartial, int* __restrict__ hist)
{
    __shared__ int skv[32];
    __shared__ float sQ[32 * 260];
    __shared__ double sred[4];

    const int t = threadIdx.x;
    const int n0 = blockIdx.x * 32;
    const int b = n0 >> 10, p0 = n0 & 1023;

    if (t < 32) skv[t] = idx[n0 + t];
    __syncthreads();

    // stage emb rows (coalesced per 8-thread group) + write qflat directly
    {
        const int r = t >> 3, c0 = (t & 7) * 32;
        const int kv = skv[r];
        const float4* src = (const float4*)(emb + (size_t)kv * D + c0);
        float4* dstL = (float4*)(sQ + r * 260 + c0);
        float4* dstG = (float4*)(out + OUT_QFLAT + (size_t)(n0 + r) * D + c0);
        #pragma unroll
        for (int g = 0; g < 8; g++) {
            float4 v = src[g];
            dstL[g] = v;
            dstG[g] = v;
        }
    }
    // enc one-hot: dense coalesced write (thread t owns cols [4t,4t+4) of every row)
    {
        float* encBase = out + OUT_ENC + (size_t)n0 * K;
        const int c0 = t * 4;
        #pragma unroll 4
        for (int r = 0; r < 32; r++) {
            const int kv = skv[r];
            float4 v = make_float4(0.f, 0.f, 0.f, 0.f);
            if (kv >= c0 && kv < c0 + 4) ((float*)&v)[kv - c0] = 1.0f;
            *(float4*)(encBase + (size_t)r * K + c0) = v;
        }
    }
    if (t < 32) atomicAdd(&hist[skv[t]], 1);
    __syncthreads();

    // qout NCHW + loss: lanes cover p (coalesced 128B per 32-lane group)
    const int p = t & 31, dg = t >> 5;
    double acc = 0.0;
    const size_t obase = (size_t)b * (D * HW) + p0 + p;
    #pragma unroll
    for (int dd = 0; dd < 32; dd++) {
        const int d = dg * 32 + dd;
        const float q = sQ[p * 260 + d];
        const float x = in[obase + (size_t)d * HW];
        out[OUT_QOUT + obase + (size_t)d * HW] = q;
        const float df = q - x;
        acc += (double)(df * df);
    }
    #pragma unroll
    for (int off = 32; off >= 1; off >>= 1) acc += __shfl_xor(acc, off, 64);
    if ((t & 63) == 0) sred[t >> 6] = acc;
    __syncthreads();
    if (t == 0) lossPartial[blockIdx.x] = sred[0] + sred[1] + sred[2] + sred[3];
}

__global__ void finalize_kernel(const int* __restrict__ hist, const double* __restrict__ lossPartial,
                                float* __restrict__ out)
{
    const int t = threadIdx.x;
    double s = 0.0;
    #pragma unroll
    for (int q = 0; q < 4; q++) {
        const int c = hist[t + q * 256];
        const double p = (double)c / (double)NTOT;
        s += p * log(p + 1e-10);
    }
    double l = 0.0;
    #pragma unroll
    for (int q = 0; q < 8; q++) l += lossPartial[t + q * 256];
    #pragma unroll
    for (int off = 32; off >= 1; off >>= 1) {
        s += __shfl_xor(s, off, 64);
        l += __shfl_xor(l, off, 64);
    }
    __shared__ double sr[4], lr[4];
    if ((t & 63) == 0) { sr[t >> 6] = s; lr[t >> 6] = l; }
    __syncthreads();
    if (t == 0) {
        out[0] = (float)(1.25 * (lr[0] + lr[1] + lr[2] + lr[3]) / (double)(NTOT * (size_t)D));
        out[OUT_PERP] = (float)exp(-(sr[0] + sr[1] + sr[2] + sr[3]));
    }
}

extern "C" void kernel_launch(void* const* d_in, const int* in_sizes, int n_in,
                              void* d_out, int out_size, void* d_ws, size_t ws_size,
                              hipStream_t stream)
{
    const float* in  = (const float*)d_in[0];   // [64,256,32,32] fp32
    const float* emb = (const float*)d_in[1];   // [1024,256] fp32
    float* out = (float*)d_out;
    char* ws = (char*)d_ws;

    int*    rcount      = (int*)(ws + 0);
    int*    hist        = (int*)(ws + 16);
    float*  enorm       = (float*)(ws + 4112);
    int*    idx         = (int*)(ws + 8208);
    int*    rlist       = (int*)(ws + 270352);
    double* lossPartial = (double*)(ws + 532496);
    ushort* efrag       = (ushort*)(ws + 548880);

    hipMemsetAsync(ws, 0, 8208, stream);                                   // rcount + hist

    enorm_kernel<<<K / 256, 256, 0, stream>>>(emb, enorm);
    esplit_kernel<<<K / 16, 256, 0, stream>>>(emb, efrag);
    score_mfma_kernel<<<NTOT / 32, 256, 0, stream>>>(in, efrag, enorm, idx, rcount, rlist);
    rescue_kernel<<<512, 256, 0, stream>>>(in, emb, rcount, rlist, idx);
    outputs_kernel<<<NTOT / 32, 256, 0, stream>>>(in, emb, idx, out, lossPartial, hist);
    finalize_kernel<<<1, 256, 0, stream>>>(hist, lossPartial, out);
}

// Round 6
// 817.036 us; speedup vs baseline: 1.2713x; 1.1170x over previous
//
#include <hip/hip_runtime.h>
#include <hip/hip_bf16.h>
#include <math.h>

// Problem constants
#define NB    64
#define D     256
#define K     1024
#define HW    1024
#define NTOT  65536
// phase-1 (bf16x3 MFMA) score error ~1.5e-7 (sigma). 1e-5 is ~60 sigma; rescue
// count ~200 rows (confirmed round 2: occupancy 1.3%, FETCH 5.8MB).
#define MARGIN 1e-5f

// Output layout (floats)
#define OUT_QOUT   1
#define OUT_PERP   16777217
#define OUT_ENC    16777218
#define OUT_QFLAT  83886082

// ws layout (bytes):
//   0      int rcount
//   8      double lossDelta          (zeroed by the 8208-byte memset)
//   16     int hist[1024]
//   4112   float enorm[1024]
//   8208   int idx[65536]            -> 270352
//   270352 int rlist[65536]          -> 532496
//   532496 double lossPartial[2048]  -> 548880
//   548880 ushort efrag[524288]      -> 1597456   (bf16 fragment-layout E, hi+lo)
// efrag layout: [h(2)][ntg(64)][dc(8)][lane(64)][j(8)] bf16
//   element = split_h( emb[ k = ntg*16 + (lane&15) ][ d = dc*32 + (lane>>4)*8 + j ] )

typedef __attribute__((ext_vector_type(8))) short bf16x8;
typedef __attribute__((ext_vector_type(4))) float f32x4;

static __device__ __forceinline__ float bf2f(ushort u) {
    return __uint_as_float(((unsigned int)u) << 16);
}

// ---- Pre-split E into MFMA B-fragment layout (hi/lo bf16) + enorm, once ----
__global__ void esplit_kernel(const float* __restrict__ emb, ushort* __restrict__ efrag,
                              float* __restrict__ enorm) {
    const int ntg = blockIdx.x;          // 64 blocks: one 16-col k-tile each
    const int t = threadIdx.x;
    __shared__ float sEm[16 * 260];      // 16 rows x 256 d, pad 4

    // stage emb rows k = ntg*16 .. +15
    {
        const int row = t >> 4, seg = t & 15;
        const float4* src = (const float4*)(emb + (size_t)(ntg * 16 + row) * D + seg * 16);
        float4* dst = (float4*)(sEm + row * 260 + seg * 16);
        #pragma unroll
        for (int q = 0; q < 4; q++) dst[q] = src[q];
    }
    __syncthreads();

    // fused enorm: 16 threads per row, shfl-reduce within the 16-lane group
    {
        const int row = t >> 4, seg = t & 15;
        float s = 0.f;
        #pragma unroll
        for (int u = 0; u < 16; u++) {
            const float v = sEm[row * 260 + seg * 16 + u];
            s += v * v;
        }
        #pragma unroll
        for (int mask = 1; mask <= 8; mask <<= 1) s += __shfl_xor(s, mask, 64);
        if (seg == 0) enorm[ntg * 16 + row] = s;
    }

    const int w = t >> 6, lane = t & 63;
    for (int fb = w; fb < 16; fb += 4) {         // fb = h*8 + dc
        const int h = fb >> 3, dc = fb & 7;
        const float* srcp = sEm + (lane & 15) * 260 + dc * 32 + (lane >> 4) * 8;
        ushort o[8];
        #pragma unroll
        for (int j = 0; j < 8; j++) {
            float x = srcp[j];
            __hip_bfloat16 hb = __float2bfloat16(x);
            if (h == 0) { o[j] = *(ushort*)&hb; }
            else {
                float hf = __bfloat162float(hb);
                __hip_bfloat16 lb = __float2bfloat16(x - hf);
                o[j] = *(ushort*)&lb;
            }
        }
        ushort* dst = efrag + ((size_t)(h * 64 + ntg) * 8 + dc) * 512 + lane * 8;
        *(int4*)dst = *(int4*)o;
    }
}

// ---- Fused phase 1: MFMA bf16x3 scores + argmin + ALL dense outputs ----
// K-loop/argmin identical to the verified round-5 structure (no spill: per-lane
// running argmin, butterflies once after the loop, waves_per_eu(2,2) for a
// 256-reg budget). New: epilogue writes qflat/enc/qout + fp64 loss partials.
// qout = emb[idx] exactly (straight-through value == q); only the LOSS needs x,
// reconstructed as hi+lo from sA (err ~1.5e-5 rel -> ~1e-9 rel on the loss).
// Rescued rows (~200) are patched later inside rescue_kernel.
__global__ void __attribute__((amdgpu_flat_work_group_size(256, 256), amdgpu_waves_per_eu(2, 2)))
score_fused_kernel(
    const float* __restrict__ in, const ushort* __restrict__ efrag,
    const float* __restrict__ enorm, const float* __restrict__ emb,
    int* __restrict__ idx, int* __restrict__ rcount, int* __restrict__ rlist,
    float* __restrict__ out, double* __restrict__ lossPartial, int* __restrict__ hist)
{
    __shared__ ushort sA[16384];   // [h(2)][mt(2)][dc(8)][lane(64)][j(8)] bf16 = 32KB
    __shared__ float  sQ[32 * 260];
    __shared__ float  sM1[128], sM2[128];
    __shared__ int    sIm[128];
    __shared__ int    skv[32];
    __shared__ double sred[4];

    const int t = threadIdx.x;
    const int n0 = blockIdx.x * 32;
    const int b = n0 >> 10, p0 = n0 & 1023;
    const int w = t >> 6, lane = t & 63;

    // Stage A (vectorized LDS writes, conflict-free; verified round 4).
    {
        #pragma unroll
        for (int i = 0; i < 4; i++) {
            const int fb = w * 4 + i;            // 0..15
            const int mt = fb >> 3, dc = fb & 7;
            const int m  = mt * 16 + (lane & 15);
            const int d0 = dc * 32 + (lane >> 4) * 8;
            const float* src = in + (size_t)b * (D * HW) + (size_t)d0 * HW + p0 + m;
            ushort oh[8], ol[8];
            #pragma unroll
            for (int j = 0; j < 8; j++) {
                const float x = src[(size_t)j * HW];
                __hip_bfloat16 hb = __float2bfloat16(x);
                const float hf = __bfloat162float(hb);
                __hip_bfloat16 lb = __float2bfloat16(x - hf);
                oh[j] = *(ushort*)&hb;
                ol[j] = *(ushort*)&lb;
            }
            ushort* dh = sA + ((0 * 2 + mt) * 8 + dc) * 512 + lane * 8;
            ushort* dl = sA + ((1 * 2 + mt) * 8 + dc) * 512 + lane * 8;
            *(int4*)dh = *(int4*)oh;
            *(int4*)dl = *(int4*)ol;
        }
    }
    __syncthreads();

    // per-lane running argmin for all 8 (mt,r) combos; q = mt*4 + r.
    float rm1[8], rm2[8]; int ri[8];
    #pragma unroll
    for (int q = 0; q < 8; q++) { rm1[q] = 3.4e38f; rm2[q] = 3.4e38f; ri[q] = 0; }

    const ushort* efragLo = efrag + 262144;

    for (int kp = 0; kp < 4; kp++) {
        f32x4 acc[2][4];
        #pragma unroll
        for (int mt = 0; mt < 2; mt++)
            #pragma unroll
            for (int c = 0; c < 4; c++) acc[mt][c] = (f32x4){0.f, 0.f, 0.f, 0.f};

        // B rotation: step s (0..15) covers dc = s>>1, col-pair cp = s&1.
        bf16x8 Bh[4][2], Bl[4][2];
        #pragma unroll
        for (int s = 0; s < 3; s++) {
            const int dc = s >> 1, cp = s & 1;
            const int ntg0 = kp * 16 + w * 4 + cp * 2;
            const size_t o0 = ((size_t)(ntg0 * 8 + dc)) * 512 + lane * 8;
            Bh[s][0] = *(const bf16x8*)(efrag + o0);
            Bl[s][0] = *(const bf16x8*)(efragLo + o0);
            Bh[s][1] = *(const bf16x8*)(efrag + o0 + 8 * 512);
            Bl[s][1] = *(const bf16x8*)(efragLo + o0 + 8 * 512);
        }

        bf16x8 ah[2], al[2];
        #pragma unroll
        for (int s = 0; s < 16; s++) {
            const int dc = s >> 1, cp = s & 1;
            if (s + 3 < 16) {
                const int s2 = s + 3, dc2 = s2 >> 1, cp2 = s2 & 1, bs2 = s2 & 3;
                const int ntg0 = kp * 16 + w * 4 + cp2 * 2;
                const size_t o0 = ((size_t)(ntg0 * 8 + dc2)) * 512 + lane * 8;
                Bh[bs2][0] = *(const bf16x8*)(efrag + o0);
                Bl[bs2][0] = *(const bf16x8*)(efragLo + o0);
                Bh[bs2][1] = *(const bf16x8*)(efrag + o0 + 8 * 512);
                Bl[bs2][1] = *(const bf16x8*)(efragLo + o0 + 8 * 512);
            }
            if (cp == 0) {   // A-frags for this dc, reused by both col-pairs
                #pragma unroll
                for (int mt = 0; mt < 2; mt++) {
                    ah[mt] = *(const bf16x8*)(sA + ((0 * 2 + mt) * 8 + dc) * 512 + lane * 8);
                    al[mt] = *(const bf16x8*)(sA + ((1 * 2 + mt) * 8 + dc) * 512 + lane * 8);
                }
            }
            const int bs = s & 3;
            #pragma unroll
            for (int mt = 0; mt < 2; mt++) {
                #pragma unroll
                for (int cc = 0; cc < 2; cc++) {
                    const int c = cp * 2 + cc;
                    acc[mt][c] = __builtin_amdgcn_mfma_f32_16x16x32_bf16(al[mt], Bh[bs][cc], acc[mt][c], 0, 0, 0);
                    acc[mt][c] = __builtin_amdgcn_mfma_f32_16x16x32_bf16(ah[mt], Bh[bs][cc], acc[mt][c], 0, 0, 0);
                    acc[mt][c] = __builtin_amdgcn_mfma_f32_16x16x32_bf16(ah[mt], Bl[bs][cc], acc[mt][c], 0, 0, 0);
                }
            }
        }

        // shuffle-free per-lane merge; kc ascending + strict '<' keeps lowest idx.
        #pragma unroll
        for (int c = 0; c < 4; c++) {
            const int kcc = kp * 256 + (w * 4 + c) * 16 + (lane & 15);
            const float envc = enorm[kcc];
            #pragma unroll
            for (int mt = 0; mt < 2; mt++)
                #pragma unroll
                for (int r = 0; r < 4; r++) {
                    const int q = mt * 4 + r;
                    const float s = envc - 2.0f * acc[mt][c][r];
                    if (s < rm1[q]) { rm2[q] = rm1[q]; rm1[q] = s; ri[q] = kcc; }
                    else if (s < rm2[q]) rm2[q] = s;
                }
        }
    }

    // 8 butterflies, once, after the K-loop (no loop state live).
    float f1 = 3.4e38f, f2 = 3.4e38f; int fi = 0;
    #pragma unroll
    for (int q = 0; q < 8; q++) {
        float m1 = rm1[q], m2 = rm2[q]; int i1 = ri[q];
        #pragma unroll
        for (int mask = 1; mask <= 8; mask <<= 1) {
            float o1 = __shfl_xor(m1, mask, 64);
            int   oi = __shfl_xor(i1, mask, 64);
            float o2 = __shfl_xor(m2, mask, 64);
            float n2 = fminf(fminf(m2, o2), fmaxf(m1, o1));
            if (o1 < m1 || (o1 == m1 && oi < i1)) { m1 = o1; i1 = oi; }
            m2 = n2;
        }
        if ((lane & 15) == q) { f1 = m1; f2 = m2; fi = i1; }
    }

    // cross-wave merge via dedicated LDS (sA stays intact for the loss phase)
    if ((lane & 15) < 8) {
        const int q = lane & 15;       // owner's combo: mt = q>>2, r = q&3
        const int row = (q >> 2) * 16 + (lane >> 4) * 4 + (q & 3);
        sM1[w * 32 + row] = f1;
        sM2[w * 32 + row] = f2;
        sIm[w * 32 + row] = fi;
    }
    __syncthreads();
    if (t < 32) {
        float b1 = sM1[t], b2 = sM2[t]; int bi = sIm[t];
        #pragma unroll
        for (int ww = 1; ww < 4; ww++) {
            float a1 = sM1[ww * 32 + t], a2 = sM2[ww * 32 + t]; int ai = sIm[ww * 32 + t];
            float n2 = fminf(fminf(b2, a2), fmaxf(b1, a1));
            if (a1 < b1 || (a1 == b1 && ai < bi)) { b1 = a1; bi = ai; }
            b2 = n2;
        }
        const int n = n0 + t;
        idx[n] = bi;
        skv[t] = bi;
        if (b2 - b1 < MARGIN) {
            int pos = atomicAdd(rcount, 1);
            rlist[pos] = n;
        }
        atomicAdd(&hist[bi], 1);
    }
    __syncthreads();

    // ---- fused epilogue (formerly outputs_kernel) ----
    // stage emb rows into sQ (coalesced, L2-resident emb) + write qflat
    {
        const int r = t >> 3, c0 = (t & 7) * 32;
        const int kv = skv[r];
        const float4* src = (const float4*)(emb + (size_t)kv * D + c0);
        float4* dstL = (float4*)(sQ + r * 260 + c0);
        float4* dstG = (float4*)(out + OUT_QFLAT + (size_t)(n0 + r) * D + c0);
        #pragma unroll
        for (int g = 0; g < 8; g++) {
            float4 v = src[g];
            dstL[g] = v;
            dstG[g] = v;
        }
    }
    // enc one-hot: dense coalesced write (thread t owns cols [4t,4t+4) of every row)
    {
        float* encBase = out + OUT_ENC + (size_t)n0 * K;
        const int c0 = t * 4;
        #pragma unroll 4
        for (int r = 0; r < 32; r++) {
            const int kv = skv[r];
            float4 v = make_float4(0.f, 0.f, 0.f, 0.f);
            if (kv >= c0 && kv < c0 + 4) ((float*)&v)[kv - c0] = 1.0f;
            *(float4*)(encBase + (size_t)r * K + c0) = v;
        }
    }
    __syncthreads();   // sQ ready

    // qout NCHW from sQ (coalesced 128B per 32-lane group; q == straight-through value)
    {
        const int p = t & 31, dg = t >> 5;
        const size_t obase = (size_t)b * (D * HW) + p0 + p;
        #pragma unroll
        for (int dd = 0; dd < 32; dd++) {
            const int d = dg * 32 + dd;
            out[OUT_QOUT + obase + (size_t)d * HW] = sQ[p * 260 + d];
        }
    }

    // loss: fragment-order walk; x = hi+lo from sA (b128 reads, conflict-free),
    // q from emb in L2. Each thread covers 32 distinct (m,d) elements.
    {
        double lacc = 0.0;
        #pragma unroll
        for (int i = 0; i < 4; i++) {
            const int fb = w * 4 + i;
            const int mt = fb >> 3, dc = fb & 7;
            const int m  = mt * 16 + (lane & 15);
            const int d0 = dc * 32 + (lane >> 4) * 8;
            const int kv = skv[m];
            bf16x8 hv = *(const bf16x8*)(sA + ((0 * 2 + mt) * 8 + dc) * 512 + lane * 8);
            bf16x8 lv = *(const bf16x8*)(sA + ((1 * 2 + mt) * 8 + dc) * 512 + lane * 8);
            const float4 q0 = *(const float4*)(emb + (size_t)kv * D + d0);
            const float4 q1 = *(const float4*)(emb + (size_t)kv * D + d0 + 4);
            float accf = 0.f;
            #pragma unroll
            for (int j = 0; j < 8; j++) {
                const float x = bf2f((ushort)hv[j]) + bf2f((ushort)lv[j]);
                const float qv = (j < 4) ? ((const float*)&q0)[j] : ((const float*)&q1)[j - 4];
                const float df = qv - x;
                accf += df * df;
            }
            lacc += (double)accf;
        }
        #pragma unroll
        for (int off = 32; off >= 1; off >>= 1) lacc += __shfl_xor(lacc, off, 64);
        if ((t & 63) == 0) sred[w] = lacc;
        __syncthreads();
        if (t == 0) lossPartial[blockIdx.x] = sred[0] + sred[1] + sred[2] + sred[3];
    }
}

// ---- Phase 2: fp64 re-score of ambiguous rows + in-place output patch ----
// For each flagged row: recompute true argmin (fp64, lowest-idx ties). If it
// differs from phase-1's pick: fix idx, enc (2 cells), hist (2 atomics),
// qflat row, qout column, and atomicAdd the fp64 loss delta.
__global__ void rescue_kernel(const float* __restrict__ in, const float* __restrict__ emb,
                              const int* __restrict__ rcount, const int* __restrict__ rlist,
                              int* __restrict__ idx, float* __restrict__ out,
                              int* __restrict__ hist, double* __restrict__ lossDelta)
{
    const int wid = blockIdx.x * 4 + (threadIdx.x >> 6);
    const int lane = threadIdx.x & 63;
    const int count = *rcount;
    for (int li = wid; li < count; li += 512 * 4) {
        const int n = rlist[li];
        const int b = n >> 10, p = n & 1023;
        const float* f = in + (size_t)b * (D * HW) + p;
        float fr[4];
        #pragma unroll
        for (int q = 0; q < 4; q++) fr[q] = f[(size_t)(lane + q * 64) * HW];
        double bm = 1e300; int bk = 0;
        #pragma unroll 1
        for (int kk = 0; kk < 16; kk++) {          // kk ascending -> lowest k on ties
            const int k = lane + kk * 64;
            const float4* er4 = (const float4*)(emb + (size_t)k * D);
            double sc[4];
            #pragma unroll
            for (int q = 0; q < 4; q++) sc[q] = 0.0;
            #pragma unroll
            for (int q = 0; q < 4; q++) {
                #pragma unroll
                for (int f4 = 0; f4 < 16; f4++) {
                    const float4 ev4 = er4[q * 16 + f4];
                    #pragma unroll
                    for (int e = 0; e < 4; e++) {
                        const int dl = f4 * 4 + e;
                        const double fv = (double)__shfl(fr[q], dl, 64);
                        const double ev = (double)((const float*)&ev4)[e];
                        sc[q] += ev * (ev - 2.0 * fv);
                    }
                }
            }
            const double s = (sc[0] + sc[1]) + (sc[2] + sc[3]);
            if (s < bm) { bm = s; bk = k; }
        }
        #pragma unroll
        for (int off = 32; off >= 1; off >>= 1) {
            double om = __shfl_xor(bm, off, 64);
            int    ok = __shfl_xor(bk, off, 64);
            if (om < bm || (om == bm && ok < bk)) { bm = om; bk = ok; }
        }

        const int old = idx[n];                       // phase-1 pick (uniform)
        if (bk != old) {
            const float* eb = emb + (size_t)bk * D;
            const float* eo = emb + (size_t)old * D;
            if (lane == 0) {
                idx[n] = bk;
                out[OUT_ENC + (size_t)n * K + old] = 0.f;
                out[OUT_ENC + (size_t)n * K + bk]  = 1.f;
                atomicAdd(&hist[old], -1);
                atomicAdd(&hist[bk], 1);
            }
            // qflat row rewrite (4 floats per lane, coalesced)
            *(float4*)(out + OUT_QFLAT + (size_t)n * D + lane * 4) =
                *(const float4*)(eb + lane * 4);
            // qout column rewrite + fp64 loss delta (lane owns d = lane + q*64)
            double dl = 0.0;
            #pragma unroll
            for (int q = 0; q < 4; q++) {
                const int d = lane + q * 64;
                const float x  = fr[q];
                const float qn = eb[d];
                const float qo = eo[d];
                out[OUT_QOUT + (size_t)b * (D * HW) + (size_t)d * HW + p] = qn;
                const double dn = (double)qn - (double)x;
                const double dO = (double)qo - (double)x;
                dl += dn * dn - dO * dO;
            }
            #pragma unroll
            for (int off = 32; off >= 1; off >>= 1) dl += __shfl_xor(dl, off, 64);
            if (lane == 0) atomicAdd(lossDelta, dl);
        }
    }
}

__global__ void finalize_kernel(const int* __restrict__ hist, const double* __restrict__ lossPartial,
                                const double* __restrict__ lossDelta, float* __restrict__ out)
{
    const int t = threadIdx.x;
    double s = 0.0;
    #pragma unroll
    for (int q = 0; q < 4; q++) {
        const int c = hist[t + q * 256];
        const double p = (double)c / (double)NTOT;
        s += p * log(p + 1e-10);
    }
    double l = 0.0;
    #pragma unroll
    for (int q = 0; q < 8; q++) l += lossPartial[t + q * 256];
    #pragma unroll
    for (int off = 32; off >= 1; off >>= 1) {
        s += __shfl_xor(s, off, 64);
        l += __shfl_xor(l, off, 64);
    }
    __shared__ double sr[4], lr[4];
    if ((t & 63) == 0) { sr[t >> 6] = s; lr[t >> 6] = l; }
    __syncthreads();
    if (t == 0) {
        const double ltot = lr[0] + lr[1] + lr[2] + lr[3] + *lossDelta;
        out[0] = (float)(1.25 * ltot / (double)(NTOT * (size_t)D));
        out[OUT_PERP] = (float)exp(-(sr[0] + sr[1] + sr[2] + sr[3]));
    }
}

extern "C" void kernel_launch(void* const* d_in, const int* in_sizes, int n_in,
                              void* d_out, int out_size, void* d_ws, size_t ws_size,
                              hipStream_t stream)
{
    const float* in  = (const float*)d_in[0];   // [64,256,32,32] fp32
    const float* emb = (const float*)d_in[1];   // [1024,256] fp32
    float* out = (float*)d_out;
    char* ws = (char*)d_ws;

    int*    rcount      = (int*)(ws + 0);
    double* lossDelta   = (double*)(ws + 8);
    int*    hist        = (int*)(ws + 16);
    float*  enorm       = (float*)(ws + 4112);
    int*    idx         = (int*)(ws + 8208);
    int*    rlist       = (int*)(ws + 270352);
    double* lossPartial = (double*)(ws + 532496);
    ushort* efrag       = (ushort*)(ws + 548880);

    hipMemsetAsync(ws, 0, 8208, stream);   // rcount + lossDelta + hist

    esplit_kernel<<<K / 16, 256, 0, stream>>>(emb, efrag, enorm);
    score_fused_kernel<<<NTOT / 32, 256, 0, stream>>>(in, efrag, enorm, emb,
                                                      idx, rcount, rlist,
                                                      out, lossPartial, hist);
    rescue_kernel<<<512, 256, 0, stream>>>(in, emb, rcount, rlist, idx, out, hist, lossDelta);
    finalize_kernel<<<1, 256, 0, stream>>>(hist, lossPartial, lossDelta, out);
}